// Round 1
// baseline (523.941 us; speedup 1.0000x reference)
//
#include <hip/hip_runtime.h>

#define NB 4096
#define NT 400
#define NCH 42
#define NH 16
#define NT4 100  // T/4

// DPP row-rotate within 16-lane rows. Direction is self-calibrated at runtime
// by applying the same DPP to the lane index, so semantics ambiguity is moot.
#define RORI(v,K) __builtin_amdgcn_update_dpp(0, (v), 0x120+(K), 0xF, 0xF, true)
#define RORF(v,K) __int_as_float(__builtin_amdgcn_update_dpp(0, __float_as_int(v), 0x120+(K), 0xF, 0xF, true))

static __device__ __forceinline__ float fast_tanh(float x) {
  float ax = __builtin_fabsf(x);
  float e  = __expf(2.0f * ax);                       // -> +inf for large ax (safe)
  float r  = __builtin_fmaf(-2.0f, __builtin_amdgcn_rcpf(e + 1.0f), 1.0f);
  return __builtin_copysignf(r, x);
}

// ---------------- Phase 1: time-parallel input projection ----------------
// P[t4][b][j] is a float4 holding steps 4*t4 .. 4*t4+3 for hidden unit j.
__global__ __launch_bounds__(128) void proj0_kernel(
    const float* __restrict__ x, const float* __restrict__ Wih0,
    const float* __restrict__ bih0, const float* __restrict__ bhh0,
    float4* __restrict__ P)
{
  __shared__ float Wl[NH * NCH];
  __shared__ float bl[NH];
  const int tid = threadIdx.x;
  for (int i = tid; i < NH * NCH; i += 128) Wl[i] = Wih0[i];
  if (tid < NH) bl[tid] = bih0[tid] + bhh0[tid];
  __syncthreads();

  const int b  = blockIdx.x;
  const int t4 = tid;
  if (t4 >= NT4) return;

  float4 acc[NH];
#pragma unroll
  for (int j = 0; j < NH; ++j) { float bb = bl[j]; acc[j] = make_float4(bb, bb, bb, bb); }

  const float* xrow = x + (size_t)b * (NCH * NT) + t4 * 4;
  for (int c = 0; c < NCH; ++c) {
    float4 xv = *(const float4*)(xrow + (size_t)c * NT);
#pragma unroll
    for (int j = 0; j < NH; ++j) {
      float w = Wl[j * NCH + c];
      acc[j].x = __builtin_fmaf(xv.x, w, acc[j].x);
      acc[j].y = __builtin_fmaf(xv.y, w, acc[j].y);
      acc[j].z = __builtin_fmaf(xv.z, w, acc[j].z);
      acc[j].w = __builtin_fmaf(xv.w, w, acc[j].w);
    }
  }
  float4* Pout = P + ((size_t)t4 * NB + b) * NH;
#pragma unroll
  for (int j = 0; j < NH; ++j) Pout[j] = acc[j];
}

// ---------------- Phase 2: sequential recurrence ----------------
// 16 lanes per batch element: lane j owns hidden unit j of both layers.
// Cross-lane matvecs via DPP row_ror folded against pre-permuted weights.
__global__ __launch_bounds__(256) void rnn_seq_kernel(
    const float4* __restrict__ P, const float* __restrict__ h0in,
    const float* __restrict__ Whh0, const float* __restrict__ Wih1,
    const float* __restrict__ Whh1, const float* __restrict__ bih1,
    const float* __restrict__ bhh1, const float* __restrict__ Wfc,
    const float* __restrict__ bfc, float* __restrict__ out)
{
  const int gtid = blockIdx.x * blockDim.x + threadIdx.x;
  const int b = gtid >> 4;
  const int j = threadIdx.x & 15;

  // Pre-permuted weights: w[k] multiplies the value DPP row_ror:k delivers.
  float w0[NH], wi1[NH], wh1[NH];
  w0[0]  = Whh0[j * NH + j];
  wi1[0] = Wih1[j * NH + j];
  wh1[0] = Whh1[j * NH + j];
#define LOADW(K) { int sj = RORI(j, K) & 15; \
  w0[K]  = Whh0[j * NH + sj]; \
  wi1[K] = Wih1[j * NH + sj]; \
  wh1[K] = Whh1[j * NH + sj]; }
  LOADW(1) LOADW(2) LOADW(3) LOADW(4) LOADW(5) LOADW(6) LOADW(7) LOADW(8)
  LOADW(9) LOADW(10) LOADW(11) LOADW(12) LOADW(13) LOADW(14) LOADW(15)
#undef LOADW
  const float b1   = bih1[j] + bhh1[j];
  const float wfc0 = Wfc[j];
  const float wfc1 = Wfc[NH + j];

  float h0 = h0in[b * NH + j];
  float h1 = h0in[(size_t)NB * NH + b * NH + j];

  const size_t pstride = (size_t)NB * NH;
  const size_t pidx    = (size_t)b * NH + j;
  float4 pc = P[pidx];

  for (int t4 = 0; t4 < NT4; ++t4) {
    const int nx = (t4 + 1 < NT4) ? (t4 + 1) : (NT4 - 1);
    float4 pn = P[pidx + (size_t)nx * pstride];   // prefetch: ~4 steps of compute hides HBM
    float pv[4] = {pc.x, pc.y, pc.z, pc.w};
#pragma unroll
    for (int q = 0; q < 4; ++q) {
      // layer 0: a = P + Whh0 . h0_prev   (two accumulators to shorten dep chain)
      float a  = __builtin_fmaf(h0, w0[0], pv[q]);
      float a2 = 0.0f;
#define L0T(K) { float hv = RORF(h0, K); \
  if ((K) & 1) a2 = __builtin_fmaf(hv, w0[K], a2); \
  else         a  = __builtin_fmaf(hv, w0[K], a); }
      L0T(1) L0T(2) L0T(3) L0T(4) L0T(5) L0T(6) L0T(7) L0T(8)
      L0T(9) L0T(10) L0T(11) L0T(12) L0T(13) L0T(14) L0T(15)
#undef L0T
      float h0n = fast_tanh(a + a2);

      // layer 1: c = b1 + Wih1 . h0n + Whh1 . h1_prev
      float c1 = __builtin_fmaf(h0n, wi1[0], b1);
      float c2 = h1 * wh1[0];
#define L1A(K) { float hv = RORF(h0n, K); \
  if ((K) & 1) c2 = __builtin_fmaf(hv, wi1[K], c2); \
  else         c1 = __builtin_fmaf(hv, wi1[K], c1); }
      L1A(1) L1A(2) L1A(3) L1A(4) L1A(5) L1A(6) L1A(7) L1A(8)
      L1A(9) L1A(10) L1A(11) L1A(12) L1A(13) L1A(14) L1A(15)
#undef L1A
#define L1B(K) { float hv = RORF(h1, K); \
  if ((K) & 1) c1 = __builtin_fmaf(hv, wh1[K], c1); \
  else         c2 = __builtin_fmaf(hv, wh1[K], c2); }
      L1B(1) L1B(2) L1B(3) L1B(4) L1B(5) L1B(6) L1B(7) L1B(8)
      L1B(9) L1B(10) L1B(11) L1B(12) L1B(13) L1B(14) L1B(15)
#undef L1B
      h1 = fast_tanh(c1 + c2);
      h0 = h0n;
    }
    pc = pn;
  }

  // FC head: out[b,n] = sum_j h1[j]*Wfc[n,j] + bfc[n]
  float v0 = h1 * wfc0;
  float v1 = h1 * wfc1;
#pragma unroll
  for (int m = 8; m >= 1; m >>= 1) {
    v0 += __shfl_xor(v0, m, 16);
    v1 += __shfl_xor(v1, m, 16);
  }
  if (j == 0) {
    float* o = out + (size_t)b * 2;
    o[0] = v0 + bfc[0];
    o[1] = v1 + bfc[1];
  }
}

extern "C" void kernel_launch(void* const* d_in, const int* in_sizes, int n_in,
                              void* d_out, int out_size, void* d_ws, size_t ws_size,
                              hipStream_t stream) {
  const float* x    = (const float*)d_in[0];
  const float* h0   = (const float*)d_in[1];
  const float* Wih0 = (const float*)d_in[2];
  const float* Whh0 = (const float*)d_in[3];
  const float* bih0 = (const float*)d_in[4];
  const float* bhh0 = (const float*)d_in[5];
  const float* Wih1 = (const float*)d_in[6];
  const float* Whh1 = (const float*)d_in[7];
  const float* bih1 = (const float*)d_in[8];
  const float* bhh1 = (const float*)d_in[9];
  const float* Wfc  = (const float*)d_in[10];
  const float* bfc  = (const float*)d_in[11];
  float* outp = (float*)d_out;
  float4* P = (float4*)d_ws;  // needs 100*4096*16*16 B = 100 MiB

  proj0_kernel<<<NB, 128, 0, stream>>>(x, Wih0, bih0, bhh0, P);
  rnn_seq_kernel<<<(NB * NH) / 256, 256, 0, stream>>>(
      P, h0, Whh0, Wih1, Whh1, bih1, bhh1, Wfc, bfc, outp);
}